// Round 3
// baseline (473.776 us; speedup 1.0000x reference)
//
#include <hip/hip_runtime.h>
#include <cmath>

#define B_ 256
#define G_ 2048
#define F_ 128
#define RNN_ 512
#define K_ 128

// ---------------------------------------------------------------------------
// One block per batch row b (256 blocks x 512 threads, ~48KB LDS, 1 block/CU).
// Phases: scorer matvec+tanh+norm -> stream node[b] (1MB) computing scores
// into LDS -> u64 radix-select (early exit) -> rank-by-count -> lse/policy ->
// gather+transpose+scale.
// Key = monotone-f32(score) << 32 | (2047-idx): all distinct, reproduces
// jax.lax.top_k ordering (desc value, asc index on ties).
// ---------------------------------------------------------------------------
__global__ __launch_bounds__(512) void k_fused(const float* __restrict__ node,
                                               const float* __restrict__ mask,
                                               const float* __restrict__ h_t,
                                               const float* __restrict__ W,
                                               const float* __restrict__ b_map,
                                               float* __restrict__ out,
                                               float* __restrict__ policy) {
    __shared__ float sc[G_];
    __shared__ unsigned hist[2][8][256];   // double-buffered privatized hists
    __shared__ unsigned long long win[K_];
    __shared__ float tile[K_][33];
    __shared__ float h[RNN_];
    __shared__ float part[4][F_];
    __shared__ alignas(16) float snorm[F_];
    __shared__ float tanhv[K_];
    __shared__ int idxk[K_];
    __shared__ float valk[K_];
    __shared__ float red8[8];
    __shared__ unsigned long long prefix_sh;
    __shared__ int need_sh;
    __shared__ int done_sh;
    __shared__ int cnt;

    const int b = blockIdx.x;
    const int tid = threadIdx.x;
    const int wv = tid >> 6;
    const int lane = tid & 63;

    // zero hist buffer 0 + control (buffer 1 is zeroed during round 0's pick)
    for (int i = tid; i < 8 * 256; i += 512) ((unsigned*)hist[0])[i] = 0u;
    if (tid == 0) { cnt = 0; done_sh = 0; }

    // ---- phase 0: scorer_norm = tanh(h W + b) / ||.|| ----
    h[tid] = h_t[b * RNN_ + tid];
    __syncthreads();
    {
        const int f = tid & 127;
        const int qu = tid >> 7;
        float acc = 0.f;
        const int r0 = qu * (RNN_ / 4);
#pragma unroll 8
        for (int r = r0; r < r0 + RNN_ / 4; ++r) acc += h[r] * W[r * F_ + f];
        part[qu][f] = acc;
    }
    __syncthreads();
    float tval = 0.f;
    if (tid < F_)
        tval = tanhf(part[0][tid] + part[1][tid] + part[2][tid] + part[3][tid] + b_map[tid]);
    {
        float v = tval * tval;  // threads >=128 contribute 0
#pragma unroll
        for (int off = 32; off; off >>= 1) v += __shfl_xor(v, off);
        if (lane == 0) red8[wv] = v;
    }
    __syncthreads();
    if (tid == 0) {
        float s = 0.f;
#pragma unroll
        for (int i = 0; i < 8; ++i) s += red8[i];
        red8[0] = sqrtf(s);
    }
    __syncthreads();
    if (tid < F_) snorm[tid] = tval / red8[0];
    __syncthreads();

    // ---- phase 1: scores into LDS (coalesced 1KB/wave-instr stream) ----
    const int half = lane >> 5;
    const int l32 = lane & 31;
    const float4 s4 = *(const float4*)&snorm[l32 * 4];
    const float4* nb = (const float4*)(node + (size_t)b * G_ * F_);
    const int gstart = wv * 256 + half;  // each wave: 256 contiguous rows
#pragma unroll 4
    for (int p = 0; p < 128; ++p) {
        const int g = gstart + p * 2;
        const float4 e = nb[(size_t)g * 32 + l32];
        float d = e.x * s4.x + e.y * s4.y + e.z * s4.z + e.w * s4.w;
        d += __shfl_xor(d, 16);
        d += __shfl_xor(d, 8);
        d += __shfl_xor(d, 4);
        d += __shfl_xor(d, 2);
        d += __shfl_xor(d, 1);
        if (l32 == 0) sc[g] = d + mask[b * G_ + g];
    }
    __syncthreads();

    // ---- build sort keys in registers ----
    unsigned long long kreg[4];
#pragma unroll
    for (int p = 0; p < 4; ++p) {
        const int i = tid + p * 512;
        unsigned u = __float_as_uint(sc[i]);
        u = (u & 0x80000000u) ? ~u : (u | 0x80000000u);
        kreg[p] = ((unsigned long long)u << 32) | (unsigned)(G_ - 1 - i);
    }

    // ---- radix select (8-bit digits, MSB first, early exit) ----
    unsigned long long prefix = 0ull;
    int need = K_;
    int round = 0;
    for (int shift = 56; shift >= 0; shift -= 8, ++round) {
        unsigned(*H)[256] = hist[round & 1];
        const unsigned long long hi_mask = (shift == 56) ? 0ull : (~0ull << (shift + 8));
#pragma unroll
        for (int p = 0; p < 4; ++p) {
            const unsigned long long key = kreg[p];
            if ((key & hi_mask) == prefix)
                atomicAdd(&H[wv][(unsigned)(key >> shift) & 255u], 1u);
        }
        __syncthreads();
        if (wv == 0) {
            const int L = lane;
            unsigned h0 = 0, h1 = 0, h2 = 0, h3 = 0;
#pragma unroll
            for (int ww = 0; ww < 8; ++ww) {
                h0 += H[ww][4 * L + 0];
                h1 += H[ww][4 * L + 1];
                h2 += H[ww][4 * L + 2];
                h3 += H[ww][4 * L + 3];
            }
            const unsigned s3 = h3, s2 = h2 + s3, s1 = h1 + s2, s0 = h0 + s1;
            unsigned S = s0;  // inclusive suffix scan across lanes
            for (int off = 1; off < 64; off <<= 1) {
                const unsigned tt = __shfl_down(S, off);
                if (L + off < 64) S += tt;
            }
            unsigned Snext = __shfl_down(S, 1);
            if (L == 63) Snext = 0;
            const unsigned un = (unsigned)need;
            const unsigned suf0 = Snext + s0, suf1 = Snext + s1;
            const unsigned suf2 = Snext + s2, suf3 = Snext + s3, suf4 = Snext;
            int d = -1;
            unsigned sd = 0, sd1 = 0;
            if (suf0 >= un && suf1 < un) { d = 4 * L + 0; sd = suf0; sd1 = suf1; }
            else if (suf1 >= un && suf2 < un) { d = 4 * L + 1; sd = suf1; sd1 = suf2; }
            else if (suf2 >= un && suf3 < un) { d = 4 * L + 2; sd = suf2; sd1 = suf3; }
            else if (suf3 >= un && suf4 < un) { d = 4 * L + 3; sd = suf3; sd1 = suf4; }
            if (d >= 0) {
                prefix_sh = prefix | ((unsigned long long)(unsigned)d << shift);
                need_sh = need - (int)sd1;
                done_sh = (sd == un);  // pool at chosen digit == need: T has zero low bits
            }
        } else {
            // waves 1-7: zero the other hist buffer for the next round
            unsigned* Z = (unsigned*)hist[(round + 1) & 1];
            for (int i = tid - 64; i < 8 * 256; i += 448) Z[i] = 0u;
        }
        __syncthreads();
        prefix = prefix_sh;
        need = need_sh;
        if (done_sh) break;
    }
    const unsigned long long T = prefix;  // exactly 128 keys >= T

    // ---- compact winners (unordered) ----
#pragma unroll
    for (int p = 0; p < 4; ++p) {
        if (kreg[p] >= T) {
            const int q = atomicAdd(&cnt, 1);
            if (q < K_) win[q] = kreg[p];
        }
    }
    __syncthreads();

    // ---- rank by counting (descending order; keys distinct) ----
    if (tid < K_) {
        const unsigned long long mykey = win[tid];
        int rank = 0;
#pragma unroll 8
        for (int j = 0; j < K_; ++j) rank += (win[j] > mykey) ? 1 : 0;
        const int idx = G_ - 1 - (int)(unsigned)(mykey & 0xFFFFFFFFull);
        idxk[rank] = idx;
        const float val = sc[idx];
        valk[rank] = val;
        tanhv[rank] = tanhf(val);
    }
    __syncthreads();

    // ---- log-sum-exp + policy score ----
    const float maxv = valk[0];  // top-1 == global max
    float s = 0.f;
#pragma unroll
    for (int p = 0; p < 4; ++p) s += expf(sc[tid + p * 512] - maxv);
#pragma unroll
    for (int off = 32; off; off >>= 1) s += __shfl_xor(s, off);
    if (lane == 0) red8[wv] = s;
    __syncthreads();
    if (tid == 0) {
        float tot = 0.f;
#pragma unroll
        for (int i = 0; i < 8; ++i) tot += red8[i];
        const float lse = maxv + logf(tot);
        float sum = 0.f;
        for (int k = 0; k < K_; ++k) sum += valk[k];
        policy[b] = sum * (1.0f / K_) - lse;
    }

    // ---- gather + transpose + scale: out[b][f][k] = node[b][idxk[k]][f]*tanh ----
    const float* nbase = node + (size_t)b * G_ * F_;
    float* ob = out + (size_t)b * F_ * K_;
    for (int f0 = 0; f0 < F_; f0 += 32) {
        for (int e = tid; e < K_ * 8; e += 512) {
            const int k2 = e >> 3;
            const int q = e & 7;
            const float4 vv = *(const float4*)(nbase + (size_t)idxk[k2] * F_ + f0 + 4 * q);
            tile[k2][4 * q + 0] = vv.x;
            tile[k2][4 * q + 1] = vv.y;
            tile[k2][4 * q + 2] = vv.z;
            tile[k2][4 * q + 3] = vv.w;
        }
        __syncthreads();
        for (int e = tid; e < 32 * K_; e += 512) {
            const int f = e >> 7;
            const int k2 = e & 127;
            ob[(size_t)(f0 + f) * K_ + k2] = tile[k2][f] * tanhv[k2];
        }
        __syncthreads();
    }
}

extern "C" void kernel_launch(void* const* d_in, const int* in_sizes, int n_in,
                              void* d_out, int out_size, void* d_ws, size_t ws_size,
                              hipStream_t stream) {
    const float* node = (const float*)d_in[0];
    const float* mask = (const float*)d_in[1];
    const float* h_t = (const float*)d_in[2];
    const float* W = (const float*)d_in[3];
    const float* bm = (const float*)d_in[4];

    float* out = (float*)d_out;                  // [B, F, K]
    float* policy = out + (size_t)B_ * F_ * K_;  // [B]

    k_fused<<<B_, 512, 0, stream>>>(node, mask, h_t, W, bm, out, policy);
}

// Round 4
// 388.970 us; speedup vs baseline: 1.2180x; 1.2180x over previous
//
#include <hip/hip_runtime.h>
#include <cmath>

#define B_ 256
#define G_ 2048
#define F_ 128
#define RNN_ 512
#define K_ 128

// ---------------------------------------------------------------------------
// Kernel 1: scorer_norm[b][f] = tanh(h_t[b]·W[:,f] + b_map[f]) / ||tanh row||
// ---------------------------------------------------------------------------
__global__ __launch_bounds__(512) void k_scorer(const float* __restrict__ h_t,
                                                const float* __restrict__ W,
                                                const float* __restrict__ b_map,
                                                float* __restrict__ scorer_norm) {
    __shared__ float h[RNN_];
    __shared__ float part[4][F_];
    __shared__ float red8[8];
    const int b = blockIdx.x;
    const int tid = threadIdx.x;
    const int wv = tid >> 6;
    const int lane = tid & 63;
    h[tid] = h_t[b * RNN_ + tid];
    __syncthreads();
    {
        const int f = tid & 127;
        const int qu = tid >> 7;
        float acc = 0.f;
        const int r0 = qu * (RNN_ / 4);
#pragma unroll 8
        for (int r = r0; r < r0 + RNN_ / 4; ++r) acc += h[r] * W[r * F_ + f];
        part[qu][f] = acc;
    }
    __syncthreads();
    float tval = 0.f;
    if (tid < F_)
        tval = tanhf(part[0][tid] + part[1][tid] + part[2][tid] + part[3][tid] + b_map[tid]);
    float v = tval * tval;
#pragma unroll
    for (int off = 32; off; off >>= 1) v += __shfl_xor(v, off);
    if (lane == 0) red8[wv] = v;
    __syncthreads();
    if (tid == 0) {
        float s = 0.f;
#pragma unroll
        for (int i = 0; i < 8; ++i) s += red8[i];
        red8[0] = sqrtf(s);
    }
    __syncthreads();
    if (tid < F_) scorer_norm[b * F_ + tid] = tval / red8[0];
}

// ---------------------------------------------------------------------------
// Kernel 2: scores[b][g] = node[b][g][:] · scorer_norm[b][:] + mask[b][g]
// grid (32, 256) x 256 thr — deep oversubscription keeps HBM at ~BW roofline.
// ---------------------------------------------------------------------------
__global__ __launch_bounds__(256) void k_scores(const float* __restrict__ node,
                                                const float* __restrict__ mask,
                                                const float* __restrict__ scorer_norm,
                                                float* __restrict__ scores) {
    const int b = blockIdx.y;
    const int gbase = blockIdx.x * 64;
    const int tid = threadIdx.x;
    const int wave = tid >> 6;
    const int lane = tid & 63;
    const int half = lane >> 5;
    const int l32 = lane & 31;

    const float4 s4 = ((const float4*)(scorer_norm + b * F_))[l32];
    const float4* nb = (const float4*)(node + (size_t)b * G_ * F_);
    const int rowbase = gbase + wave * 16;
#pragma unroll
    for (int p = 0; p < 8; ++p) {
        const int g = rowbase + p * 2 + half;
        const float4 e = nb[(size_t)g * 32 + l32];
        float part = e.x * s4.x + e.y * s4.y + e.z * s4.z + e.w * s4.w;
        part += __shfl_xor(part, 16);
        part += __shfl_xor(part, 8);
        part += __shfl_xor(part, 4);
        part += __shfl_xor(part, 2);
        part += __shfl_xor(part, 1);
        if (l32 == 0) scores[b * G_ + g] = part + mask[b * G_ + g];
    }
}

// ---------------------------------------------------------------------------
// Kernel 3: per-b exact top-128 via u64 radix-select with early exit,
// rank-by-count ordering, log-softmax policy. Writes idxk/tanhv to ws.
// 256 blocks x 512 threads, ~27 KB LDS.
// ---------------------------------------------------------------------------
__global__ __launch_bounds__(512) void k_select(const float* __restrict__ scores,
                                                int* __restrict__ idxk_g,
                                                float* __restrict__ tanhv_g,
                                                float* __restrict__ policy) {
    __shared__ float sc[G_];
    __shared__ unsigned hist[2][8][256];
    __shared__ unsigned long long win[K_];
    __shared__ float valk[K_];
    __shared__ float red8[8];
    __shared__ unsigned long long prefix_sh;
    __shared__ int need_sh;
    __shared__ int done_sh;
    __shared__ int cnt;

    const int b = blockIdx.x;
    const int tid = threadIdx.x;
    const int wv = tid >> 6;
    const int lane = tid & 63;

    for (int i = tid; i < 8 * 256; i += 512) ((unsigned*)hist[0])[i] = 0u;
    if (tid == 0) { cnt = 0; done_sh = 0; }

    unsigned long long kreg[4];
#pragma unroll
    for (int p = 0; p < 4; ++p) {
        const int i = tid + p * 512;
        const float v = scores[b * G_ + i];
        sc[i] = v;
        unsigned u = __float_as_uint(v);
        u = (u & 0x80000000u) ? ~u : (u | 0x80000000u);
        kreg[p] = ((unsigned long long)u << 32) | (unsigned)(G_ - 1 - i);
    }
    __syncthreads();

    // ---- radix select (MSB-first 8-bit digits, early exit) ----
    unsigned long long prefix = 0ull;
    int need = K_;
    int round = 0;
    for (int shift = 56; shift >= 0; shift -= 8, ++round) {
        unsigned(*H)[256] = hist[round & 1];
        const unsigned long long hi_mask = (shift == 56) ? 0ull : (~0ull << (shift + 8));
#pragma unroll
        for (int p = 0; p < 4; ++p) {
            const unsigned long long key = kreg[p];
            if ((key & hi_mask) == prefix)
                atomicAdd(&H[wv][(unsigned)(key >> shift) & 255u], 1u);
        }
        __syncthreads();
        if (wv == 0) {
            const int L = lane;
            unsigned h0 = 0, h1 = 0, h2 = 0, h3 = 0;
#pragma unroll
            for (int ww = 0; ww < 8; ++ww) {
                h0 += H[ww][4 * L + 0];
                h1 += H[ww][4 * L + 1];
                h2 += H[ww][4 * L + 2];
                h3 += H[ww][4 * L + 3];
            }
            const unsigned s3 = h3, s2 = h2 + s3, s1 = h1 + s2, s0 = h0 + s1;
            unsigned S = s0;
            for (int off = 1; off < 64; off <<= 1) {
                const unsigned tt = __shfl_down(S, off);
                if (L + off < 64) S += tt;
            }
            unsigned Snext = __shfl_down(S, 1);
            if (L == 63) Snext = 0;
            const unsigned un = (unsigned)need;
            const unsigned suf0 = Snext + s0, suf1 = Snext + s1;
            const unsigned suf2 = Snext + s2, suf3 = Snext + s3, suf4 = Snext;
            int d = -1;
            unsigned sd = 0, sd1 = 0;
            if (suf0 >= un && suf1 < un) { d = 4 * L + 0; sd = suf0; sd1 = suf1; }
            else if (suf1 >= un && suf2 < un) { d = 4 * L + 1; sd = suf1; sd1 = suf2; }
            else if (suf2 >= un && suf3 < un) { d = 4 * L + 2; sd = suf2; sd1 = suf3; }
            else if (suf3 >= un && suf4 < un) { d = 4 * L + 3; sd = suf3; sd1 = suf4; }
            if (d >= 0) {
                prefix_sh = prefix | ((unsigned long long)(unsigned)d << shift);
                need_sh = need - (int)sd1;
                done_sh = (sd == un);
            }
        } else {
            unsigned* Z = (unsigned*)hist[(round + 1) & 1];
            for (int i = tid - 64; i < 8 * 256; i += 448) Z[i] = 0u;
        }
        __syncthreads();
        prefix = prefix_sh;
        need = need_sh;
        if (done_sh) break;
    }
    const unsigned long long T = prefix;  // exactly 128 keys >= T

    // ---- compact winners ----
#pragma unroll
    for (int p = 0; p < 4; ++p) {
        if (kreg[p] >= T) {
            const int q = atomicAdd(&cnt, 1);
            if (q < K_) win[q] = kreg[p];
        }
    }
    __syncthreads();

    // ---- rank by counting (keys distinct -> exact permutation) ----
    if (tid < K_) {
        const unsigned long long mykey = win[tid];
        int rank = 0;
#pragma unroll 8
        for (int j = 0; j < K_; ++j) rank += (win[j] > mykey) ? 1 : 0;
        const int idx = G_ - 1 - (int)(unsigned)(mykey & 0xFFFFFFFFull);
        const float val = sc[idx];
        idxk_g[b * K_ + rank] = idx;
        valk[rank] = val;
        tanhv_g[b * K_ + rank] = tanhf(val);
    }
    __syncthreads();

    // ---- log-sum-exp + policy ----
    const float maxv = valk[0];
    float s = 0.f;
#pragma unroll
    for (int p = 0; p < 4; ++p) s += expf(sc[tid + p * 512] - maxv);
#pragma unroll
    for (int off = 32; off; off >>= 1) s += __shfl_xor(s, off);
    if (lane == 0) red8[wv] = s;
    __syncthreads();
    if (tid == 0) {
        float tot = 0.f;
#pragma unroll
        for (int i = 0; i < 8; ++i) tot += red8[i];
        const float lse = maxv + logf(tot);
        float sum = 0.f;
        for (int k = 0; k < K_; ++k) sum += valk[k];
        policy[b] = sum * (1.0f / K_) - lse;
    }
}

// ---------------------------------------------------------------------------
// Kernel 4: out[b][f][k] = node[b][idxk[k]][f] * tanhv[k]
// grid (4, B) x 256 thr: each block transposes a 32f x 128k tile.
// ---------------------------------------------------------------------------
__global__ __launch_bounds__(256) void k_gather(const float* __restrict__ node,
                                                const int* __restrict__ idxk_g,
                                                const float* __restrict__ tanhv_g,
                                                float* __restrict__ out) {
    __shared__ float tile[K_][33];
    __shared__ int idxk[K_];
    __shared__ float tanhv[K_];
    const int b = blockIdx.y;
    const int f0 = blockIdx.x * 32;
    const int tid = threadIdx.x;

    if (tid < K_) {
        idxk[tid] = idxk_g[b * K_ + tid];
        tanhv[tid] = tanhv_g[b * K_ + tid];
    }
    __syncthreads();

    const float* nb = node + (size_t)b * G_ * F_;
#pragma unroll
    for (int i = 0; i < 4; ++i) {
        const int e = tid + i * 256;
        const int k2 = e >> 3;
        const int q = e & 7;
        const float4 v = *(const float4*)(nb + (size_t)idxk[k2] * F_ + f0 + 4 * q);
        tile[k2][4 * q + 0] = v.x;
        tile[k2][4 * q + 1] = v.y;
        tile[k2][4 * q + 2] = v.z;
        tile[k2][4 * q + 3] = v.w;
    }
    __syncthreads();

    float* ob = out + (size_t)b * F_ * K_;
#pragma unroll
    for (int i = 0; i < 16; ++i) {
        const int e = tid + i * 256;
        const int f = e >> 7;
        const int k2 = e & 127;
        ob[(size_t)(f0 + f) * K_ + k2] = tile[k2][f] * tanhv[k2];
    }
}

extern "C" void kernel_launch(void* const* d_in, const int* in_sizes, int n_in,
                              void* d_out, int out_size, void* d_ws, size_t ws_size,
                              hipStream_t stream) {
    const float* node = (const float*)d_in[0];
    const float* mask = (const float*)d_in[1];
    const float* h_t = (const float*)d_in[2];
    const float* W = (const float*)d_in[3];
    const float* bm = (const float*)d_in[4];

    float* out = (float*)d_out;                  // [B, F, K]
    float* policy = out + (size_t)B_ * F_ * K_;  // [B]

    float* scorer_norm = (float*)d_ws;           // B*F
    float* scores = scorer_norm + B_ * F_;       // B*G
    int* idxk_g = (int*)(scores + B_ * G_);      // B*K
    float* tanhv_g = (float*)(idxk_g + B_ * K_); // B*K

    k_scorer<<<B_, 512, 0, stream>>>(h_t, W, bm, scorer_norm);
    k_scores<<<dim3(G_ / 64, B_), 256, 0, stream>>>(node, mask, scorer_norm, scores);
    k_select<<<B_, 512, 0, stream>>>(scores, idxk_g, tanhv_g, policy);
    k_gather<<<dim3(4, B_), 256, 0, stream>>>(node, idxk_g, tanhv_g, out);
}

// Round 5
// 388.215 us; speedup vs baseline: 1.2204x; 1.0019x over previous
//
#include <hip/hip_runtime.h>
#include <cmath>

#define B_ 256
#define G_ 2048
#define F_ 128
#define RNN_ 512
#define K_ 128

// ---------------------------------------------------------------------------
// Kernel 1: scorer_norm[b][f] = tanh(h_t[b]·W[:,f] + b_map[f]) / ||tanh row||
// ---------------------------------------------------------------------------
__global__ __launch_bounds__(512) void k_scorer(const float* __restrict__ h_t,
                                                const float* __restrict__ W,
                                                const float* __restrict__ b_map,
                                                float* __restrict__ scorer_norm) {
    __shared__ float h[RNN_];
    __shared__ float part[4][F_];
    __shared__ float red8[8];
    const int b = blockIdx.x;
    const int tid = threadIdx.x;
    const int wv = tid >> 6;
    const int lane = tid & 63;
    h[tid] = h_t[b * RNN_ + tid];
    __syncthreads();
    {
        const int f = tid & 127;
        const int qu = tid >> 7;
        float acc = 0.f;
        const int r0 = qu * (RNN_ / 4);
#pragma unroll 8
        for (int r = r0; r < r0 + RNN_ / 4; ++r) acc += h[r] * W[r * F_ + f];
        part[qu][f] = acc;
    }
    __syncthreads();
    float tval = 0.f;
    if (tid < F_)
        tval = tanhf(part[0][tid] + part[1][tid] + part[2][tid] + part[3][tid] + b_map[tid]);
    float v = tval * tval;
#pragma unroll
    for (int off = 32; off; off >>= 1) v += __shfl_xor(v, off);
    if (lane == 0) red8[wv] = v;
    __syncthreads();
    if (tid == 0) {
        float s = 0.f;
#pragma unroll
        for (int i = 0; i < 8; ++i) s += red8[i];
        red8[0] = sqrtf(s);
    }
    __syncthreads();
    if (tid < F_) scorer_norm[b * F_ + tid] = tval / red8[0];
}

// ---------------------------------------------------------------------------
// Kernel 2: scores[b][g] = node[b][g][:] · scorer_norm[b][:] + mask[b][g]
// grid (32, 256) x 256 thr — deep oversubscription, ~BW roofline.
// ---------------------------------------------------------------------------
__global__ __launch_bounds__(256) void k_scores(const float* __restrict__ node,
                                                const float* __restrict__ mask,
                                                const float* __restrict__ scorer_norm,
                                                float* __restrict__ scores) {
    const int b = blockIdx.y;
    const int gbase = blockIdx.x * 64;
    const int tid = threadIdx.x;
    const int wave = tid >> 6;
    const int lane = tid & 63;
    const int half = lane >> 5;
    const int l32 = lane & 31;

    const float4 s4 = ((const float4*)(scorer_norm + b * F_))[l32];
    const float4* nb = (const float4*)(node + (size_t)b * G_ * F_);
    const int rowbase = gbase + wave * 16;
#pragma unroll
    for (int p = 0; p < 8; ++p) {
        const int g = rowbase + p * 2 + half;
        const float4 e = nb[(size_t)g * 32 + l32];
        float part = e.x * s4.x + e.y * s4.y + e.z * s4.z + e.w * s4.w;
        part += __shfl_xor(part, 16);
        part += __shfl_xor(part, 8);
        part += __shfl_xor(part, 4);
        part += __shfl_xor(part, 2);
        part += __shfl_xor(part, 1);
        if (l32 == 0) scores[b * G_ + g] = part + mask[b * G_ + g];
    }
}

// ---------------------------------------------------------------------------
// Kernel 3: per-b top-128 (u64 radix-select, early exit, rank-by-count),
// log-softmax policy, then in-block gather+transpose+tanh-scale.
// 256 blocks x 512 threads, ~44 KB LDS.
// ---------------------------------------------------------------------------
__global__ __launch_bounds__(512) void k_selgather(const float* __restrict__ scores,
                                                   const float* __restrict__ node,
                                                   float* __restrict__ out,
                                                   float* __restrict__ policy) {
    __shared__ float sc[G_];
    __shared__ unsigned hist[2][8][256];
    __shared__ unsigned long long win[K_];
    __shared__ float tile[K_][33];
    __shared__ float valk[K_];
    __shared__ float tanhv[K_];
    __shared__ int idxk[K_];
    __shared__ float red8[8];
    __shared__ unsigned long long prefix_sh;
    __shared__ int need_sh;
    __shared__ int done_sh;
    __shared__ int cnt;

    const int b = blockIdx.x;
    const int tid = threadIdx.x;
    const int wv = tid >> 6;
    const int lane = tid & 63;

    for (int i = tid; i < 8 * 256; i += 512) ((unsigned*)hist[0])[i] = 0u;
    if (tid == 0) { cnt = 0; done_sh = 0; }

    // single coalesced float4 pass: thread tid owns scores[4*tid .. 4*tid+3]
    unsigned long long kreg[4];
    {
        const float4 v4 = ((const float4*)(scores + b * G_))[tid];
        const float vv[4] = {v4.x, v4.y, v4.z, v4.w};
#pragma unroll
        for (int p = 0; p < 4; ++p) {
            const int i = tid * 4 + p;
            sc[i] = vv[p];
            unsigned u = __float_as_uint(vv[p]);
            u = (u & 0x80000000u) ? ~u : (u | 0x80000000u);
            kreg[p] = ((unsigned long long)u << 32) | (unsigned)(G_ - 1 - i);
        }
    }
    __syncthreads();

    // ---- radix select (MSB-first 8-bit digits, early exit) ----
    unsigned long long prefix = 0ull;
    int need = K_;
    int round = 0;
    for (int shift = 56; shift >= 0; shift -= 8, ++round) {
        unsigned(*H)[256] = hist[round & 1];
        const unsigned long long hi_mask = (shift == 56) ? 0ull : (~0ull << (shift + 8));
#pragma unroll
        for (int p = 0; p < 4; ++p) {
            const unsigned long long key = kreg[p];
            if ((key & hi_mask) == prefix)
                atomicAdd(&H[wv][(unsigned)(key >> shift) & 255u], 1u);
        }
        __syncthreads();
        if (wv == 0) {
            const int L = lane;
            unsigned h0 = 0, h1 = 0, h2 = 0, h3 = 0;
#pragma unroll
            for (int ww = 0; ww < 8; ++ww) {
                h0 += H[ww][4 * L + 0];
                h1 += H[ww][4 * L + 1];
                h2 += H[ww][4 * L + 2];
                h3 += H[ww][4 * L + 3];
            }
            const unsigned s3 = h3, s2 = h2 + s3, s1 = h1 + s2, s0 = h0 + s1;
            unsigned S = s0;
            for (int off = 1; off < 64; off <<= 1) {
                const unsigned tt = __shfl_down(S, off);
                if (L + off < 64) S += tt;
            }
            unsigned Snext = __shfl_down(S, 1);
            if (L == 63) Snext = 0;
            const unsigned un = (unsigned)need;
            const unsigned suf0 = Snext + s0, suf1 = Snext + s1;
            const unsigned suf2 = Snext + s2, suf3 = Snext + s3, suf4 = Snext;
            int d = -1;
            unsigned sd = 0, sd1 = 0;
            if (suf0 >= un && suf1 < un) { d = 4 * L + 0; sd = suf0; sd1 = suf1; }
            else if (suf1 >= un && suf2 < un) { d = 4 * L + 1; sd = suf1; sd1 = suf2; }
            else if (suf2 >= un && suf3 < un) { d = 4 * L + 2; sd = suf2; sd1 = suf3; }
            else if (suf3 >= un && suf4 < un) { d = 4 * L + 3; sd = suf3; sd1 = suf4; }
            if (d >= 0) {
                prefix_sh = prefix | ((unsigned long long)(unsigned)d << shift);
                need_sh = need - (int)sd1;
                done_sh = (sd == un);
            }
        } else {
            unsigned* Z = (unsigned*)hist[(round + 1) & 1];
            for (int i = tid - 64; i < 8 * 256; i += 448) Z[i] = 0u;
        }
        __syncthreads();
        prefix = prefix_sh;
        need = need_sh;
        if (done_sh) break;
    }
    const unsigned long long T = prefix;  // exactly 128 keys >= T

    // ---- compact winners (unordered) ----
#pragma unroll
    for (int p = 0; p < 4; ++p) {
        if (kreg[p] >= T) {
            const int q = atomicAdd(&cnt, 1);
            if (q < K_) win[q] = kreg[p];
        }
    }
    __syncthreads();

    // ---- rank by counting (keys distinct -> exact permutation) ----
    if (tid < K_) {
        const unsigned long long mykey = win[tid];
        int rank = 0;
#pragma unroll 8
        for (int j = 0; j < K_; ++j) rank += (win[j] > mykey) ? 1 : 0;
        const int idx = G_ - 1 - (int)(unsigned)(mykey & 0xFFFFFFFFull);
        const float val = sc[idx];
        idxk[rank] = idx;
        valk[rank] = val;
        tanhv[rank] = tanhf(val);
    }
    __syncthreads();

    // ---- log-sum-exp + policy ----
    const float maxv = valk[0];
    float s = 0.f;
#pragma unroll
    for (int p = 0; p < 4; ++p) s += expf(sc[tid + p * 512] - maxv);
#pragma unroll
    for (int off = 32; off; off >>= 1) s += __shfl_xor(s, off);
    if (lane == 0) red8[wv] = s;
    __syncthreads();
    if (tid == 0) {
        float tot = 0.f;
#pragma unroll
        for (int i = 0; i < 8; ++i) tot += red8[i];
        const float lse = maxv + logf(tot);
        float sum = 0.f;
        for (int k = 0; k < K_; ++k) sum += valk[k];
        policy[b] = sum * (1.0f / K_) - lse;
    }

    // ---- gather + transpose + scale: out[b][f][k] = node[b][idxk[k]][f]*tanh ----
    const float* nbase = node + (size_t)b * G_ * F_;
    float* ob = out + (size_t)b * F_ * K_;
    for (int f0 = 0; f0 < F_; f0 += 32) {
        for (int e = tid; e < K_ * 8; e += 512) {
            const int k2 = e >> 3;
            const int q = e & 7;
            const float4 vv = *(const float4*)(nbase + (size_t)idxk[k2] * F_ + f0 + 4 * q);
            tile[k2][4 * q + 0] = vv.x;
            tile[k2][4 * q + 1] = vv.y;
            tile[k2][4 * q + 2] = vv.z;
            tile[k2][4 * q + 3] = vv.w;
        }
        __syncthreads();
        for (int e = tid; e < 32 * K_; e += 512) {
            const int f = e >> 7;
            const int k2 = e & 127;
            ob[(size_t)(f0 + f) * K_ + k2] = tile[k2][f] * tanhv[k2];
        }
        __syncthreads();
    }
}

extern "C" void kernel_launch(void* const* d_in, const int* in_sizes, int n_in,
                              void* d_out, int out_size, void* d_ws, size_t ws_size,
                              hipStream_t stream) {
    const float* node = (const float*)d_in[0];
    const float* mask = (const float*)d_in[1];
    const float* h_t = (const float*)d_in[2];
    const float* W = (const float*)d_in[3];
    const float* bm = (const float*)d_in[4];

    float* out = (float*)d_out;                  // [B, F, K]
    float* policy = out + (size_t)B_ * F_ * K_;  // [B]

    float* scorer_norm = (float*)d_ws;           // B*F
    float* scores = scorer_norm + B_ * F_;       // B*G

    k_scorer<<<B_, 512, 0, stream>>>(h_t, W, bm, scorer_norm);
    k_scores<<<dim3(G_ / 64, B_), 256, 0, stream>>>(node, mask, scorer_norm, scores);
    k_selgather<<<B_, 512, 0, stream>>>(scores, node, out, policy);
}